// Round 5
// baseline (152.827 us; speedup 1.0000x reference)
//
#include <hip/hip_runtime.h>
#include <hip/hip_bf16.h>
#include <math.h>

// GNNAngle: per node, 16 neighbor vectors (D=32) -> normalize -> 120 pairwise
// angles -> MLP 120->128->128->128->1 (tanh,tanh,tanh,sigmoid).
// Round 5: occupancy push. 256-thread blocks (32 nodes), LDS 17.4 KB,
// __launch_bounds__(256,8) -> 8 blocks/CU, 32 waves/CU. Phase B restructured
// (sequential j-tiles, acts reloaded per node-tile) to fit the 64-VGPR cap.

#define CHUNK     32    // nodes per block
#define NTHREADS  256   // 4 waves
#define ASTRIDE   136   // f16 act row stride (b128 conflict-free in MLP)

typedef _Float16 f16;
typedef f16  f16x8 __attribute__((ext_vector_type(8)));
typedef f16  f16x4 __attribute__((ext_vector_type(4)));
typedef float f32x4 __attribute__((ext_vector_type(4)));

__device__ __forceinline__ float fast_tanh(float x) {
    float e = __expf(2.0f * x);
    return 1.0f - 2.0f * __builtin_amdgcn_rcpf(e + 1.0f);
}

__device__ __forceinline__ float fast_acos(float x) {
    // Abramowitz-Stegun 4.4.45: max abs error 6.7e-5 rad, branchless
    float ax = fabsf(x);
    float p = fmaf(-0.0187293f, ax, 0.0742610f);
    p = fmaf(p, ax, -0.2121144f);
    p = fmaf(p, ax, 1.5707288f);
    float r = sqrtf(1.0f - ax) * p;          // acos(|x|)
    return (x >= 0.0f) ? r : (3.14159265358979f - r);
}

// ---- prep: W[i][j] (f32, row-major [IN][128]) -> Wt[j][i] f16 [128][128], K zero-padded
__global__ void prep_weights(const float* __restrict__ W1,
                             const float* __restrict__ W2,
                             const float* __restrict__ W3,
                             f16* __restrict__ wt)
{
    int tid = blockIdx.x * 256 + threadIdx.x;
    if (tid >= 3 * 128 * 128) return;
    int layer = tid >> 14;
    int rem   = tid & 16383;
    int j     = rem >> 7;
    int i     = rem & 127;
    const float* W = (layer == 0) ? W1 : ((layer == 1) ? W2 : W3);
    int in_l = (layer == 0) ? 120 : 128;
    float v = (i < in_l) ? W[i * 128 + j] : 0.0f;
    wt[tid] = (f16)v;   // wt[layer][j][i]
}

// one MLP layer: dst[node][j] = tanh(sum_i src[node][i]*W[i][j] + b[j])
// wave w owns j-tiles {2w, 2w+1}, iterates both 16-node tiles of the chunk.
// Sequential j-tiles keep only 16 VGPRs of weights live (fits 64-VGPR cap).
__device__ __forceinline__ void mlp_layer_mfma(const f16* __restrict__ wl,   // [128][128] f16 ([j][i])
                                               const float* __restrict__ bias,
                                               const f16* src, f16* dst,     // LDS, stride ASTRIDE
                                               int w, int lr, int lg)
{
    #pragma unroll
    for (int jj = 0; jj < 2; ++jj) {
        const int jt = w * 2 + jj;
        const f16* wr = wl + (jt * 16 + lr) * 128 + lg * 8;
        f16x8 a0 = *(const f16x8*)(wr);
        f16x8 a1 = *(const f16x8*)(wr + 32);
        f16x8 a2 = *(const f16x8*)(wr + 64);
        f16x8 a3 = *(const f16x8*)(wr + 96);
        f32x4 bv = *(const f32x4*)(bias + jt * 16 + lg * 4);
        #pragma unroll
        for (int nt = 0; nt < 2; ++nt) {
            const int node = nt * 16 + lr;
            const f16* sr = src + node * ASTRIDE + lg * 8;
            f16x8 bf0 = *(const f16x8*)(sr);
            f16x8 bf1 = *(const f16x8*)(sr + 32);
            f16x8 bf2 = *(const f16x8*)(sr + 64);
            f16x8 bf3 = *(const f16x8*)(sr + 96);
            f32x4 acc = {0.f, 0.f, 0.f, 0.f};
            acc = __builtin_amdgcn_mfma_f32_16x16x32_f16(a0, bf0, acc, 0, 0, 0);
            acc = __builtin_amdgcn_mfma_f32_16x16x32_f16(a1, bf1, acc, 0, 0, 0);
            acc = __builtin_amdgcn_mfma_f32_16x16x32_f16(a2, bf2, acc, 0, 0, 0);
            acc = __builtin_amdgcn_mfma_f32_16x16x32_f16(a3, bf3, acc, 0, 0, 0);
            // D[row=j_local=lg*4+r][col=node=lr]; bias+tanh -> f16 -> LDS
            f16x4 o;
            #pragma unroll
            for (int r = 0; r < 4; ++r)
                o[r] = (f16)fast_tanh(acc[r] + bv[r]);
            *(f16x4*)(dst + node * ASTRIDE + jt * 16 + lg * 4) = o;
        }
    }
}

__global__ __launch_bounds__(NTHREADS, 8)
void gnn_angle_fused(const float* __restrict__ edge_attr,
                     const f16*   __restrict__ wt,     // 3x[128][128] f16
                     const float* __restrict__ b1, const float* __restrict__ b2,
                     const float* __restrict__ b3,
                     const float* __restrict__ W4, const float* __restrict__ b4,
                     float* __restrict__ out, int n_nodes)
{
    __shared__ __attribute__((aligned(16))) f16 actA[CHUNK * ASTRIDE];
    __shared__ __attribute__((aligned(16))) f16 actB[CHUNK * ASTRIDE];

    const int t = threadIdx.x;
    const int w = t >> 6;    // wave 0..3
    const int l = t & 63;
    const int base = blockIdx.x * CHUNK;
    const int lr = l & 15;
    const int lg = l >> 4;

    // ---------------- Phase A: normalize + Gram via MFMA + acos ----------------
    // 2-deep pipeline: iteration it+1's global loads issue before it's compute.
    const float* srcw = edge_attr + (long)(base + w) * 512 + lr * 32 + lg * 8;
    float4 c0 = make_float4(0.f, 0.f, 0.f, 0.f), c1 = c0;
    if ((long)base + w < n_nodes) {
        c0 = *(const float4*)(srcw);
        c1 = *(const float4*)(srcw + 4);
    }
    for (int it = 0; it < 8; ++it) {
        const int m = it * 4 + w;                // local node 0..31
        float4 n0 = make_float4(0.f, 0.f, 0.f, 0.f), n1 = n0;
        if (it < 7 && (long)base + m + 4 < n_nodes) {
            const float* s = srcw + (it + 1) * 4 * 512;
            n0 = *(const float4*)(s);
            n1 = *(const float4*)(s + 4);
        }
        float ss = c0.x*c0.x + c0.y*c0.y + c0.z*c0.z + c0.w*c0.w
                 + c1.x*c1.x + c1.y*c1.y + c1.z*c1.z + c1.w*c1.w;
        ss += __shfl_xor(ss, 16);
        ss += __shfl_xor(ss, 32);                // row (lr) norm across lg lanes
        const float sc = __builtin_amdgcn_rsqf(ss + 1e-24f);
        f16x8 frag;
        frag[0] = (f16)(c0.x * sc); frag[1] = (f16)(c0.y * sc);
        frag[2] = (f16)(c0.z * sc); frag[3] = (f16)(c0.w * sc);
        frag[4] = (f16)(c1.x * sc); frag[5] = (f16)(c1.y * sc);
        frag[6] = (f16)(c1.z * sc); frag[7] = (f16)(c1.w * sc);
        f32x4 acc = {0.f, 0.f, 0.f, 0.f};
        acc = __builtin_amdgcn_mfma_f32_16x16x32_f16(frag, frag, acc, 0, 0, 0);
        // zero-pad feats 120..127 (K padding for layer 1)
        if (l < 8) actA[m * ASTRIDE + 120 + l] = (f16)0.f;
        // upper triangle: lane holds cos for col=lr, rows lg*4+r
        const int col = lr;
        #pragma unroll
        for (int r2 = 0; r2 < 4; ++r2) {
            const int row = lg * 4 + r2;
            float c = fminf(fmaxf(acc[r2], -1.0f + 1e-7f), 1.0f - 1e-7f);
            float ang = fast_acos(c);            // branchless, unconditional
            if (row < col) {
                const int p = 15 * row - ((row * (row - 1)) >> 1) + (col - row - 1);
                actA[m * ASTRIDE + p] = (f16)ang;
            }
        }
        c0 = n0; c1 = n1;
    }
    __syncthreads();

    // ---------------- Phase B: MLP on MFMA ----------------
    mlp_layer_mfma(wt,             b1, actA, actB, w, lr, lg);
    __syncthreads();
    mlp_layer_mfma(wt + 16384,     b2, actB, actA, w, lr, lg);
    __syncthreads();
    mlp_layer_mfma(wt + 2 * 16384, b3, actA, actB, w, lr, lg);
    __syncthreads();

    // ---------------- final 128->1 + sigmoid: 8 threads per node ----------------
    {
        const int node = t >> 3;       // 0..31
        const int part = t & 7;        // 0..7
        const int i0 = part * 16;
        const f16* sr = actB + node * ASTRIDE + i0;
        f16x8 h0 = *(const f16x8*)(sr);
        f16x8 h1 = *(const f16x8*)(sr + 8);
        float s = 0.f;
        #pragma unroll
        for (int e = 0; e < 8; ++e) s = fmaf((float)h0[e], W4[i0 + e], s);
        #pragma unroll
        for (int e = 0; e < 8; ++e) s = fmaf((float)h1[e], W4[i0 + 8 + e], s);
        s += __shfl_xor(s, 1);
        s += __shfl_xor(s, 2);
        s += __shfl_xor(s, 4);
        if (part == 0) {
            const long g = (long)base + node;
            if (g < n_nodes)
                out[g] = __builtin_amdgcn_rcpf(1.0f + __expf(-(s + b4[0])));
        }
    }
}

extern "C" void kernel_launch(void* const* d_in, const int* in_sizes, int n_in,
                              void* d_out, int out_size, void* d_ws, size_t ws_size,
                              hipStream_t stream) {
    // inputs: 0:x 1:edge_index 2:edge_attr 3:k 4:W1 5:b1 6:W2 7:b2 8:W3 9:b3 10:W4 11:b4
    const float* edge_attr = (const float*)d_in[2];
    const float* W1 = (const float*)d_in[4];
    const float* b1 = (const float*)d_in[5];
    const float* W2 = (const float*)d_in[6];
    const float* b2 = (const float*)d_in[7];
    const float* W3 = (const float*)d_in[8];
    const float* b3 = (const float*)d_in[9];
    const float* W4 = (const float*)d_in[10];
    const float* b4 = (const float*)d_in[11];
    float* out = (float*)d_out;
    f16* wt = (f16*)d_ws;                        // 3*128*128 f16 = 96 KB

    const int n_nodes = in_sizes[2] / 512;       // E*D / (16*32)

    prep_weights<<<(3 * 128 * 128 + 255) / 256, 256, 0, stream>>>(W1, W2, W3, wt);

    const int blocks = (n_nodes + CHUNK - 1) / CHUNK;
    gnn_angle_fused<<<blocks, NTHREADS, 0, stream>>>(
        edge_attr, wt, b1, b2, b3, W4, b4, out, n_nodes);
}